// Round 1
// baseline (930.610 us; speedup 1.0000x reference)
//
#include <hip/hip_runtime.h>

#define NB   32      // batch
#define DIM  4096
#define HQ   32
#define HKV  8
#define HD   128
#define MAXS 2048

// ---------------------------------------------------------------------------
// GEMV-32: C[b, r] += sum_k W[r,k] * X[b,k]   for 32 batch rows at once.
// Grid: (M/64, KSPLIT). Each block: 64 rows x 32 b, K-slice of K/KSPLIT.
// Partials combined via fp32 atomicAdd (targets pre-zeroed).
// ---------------------------------------------------------------------------
__global__ __launch_bounds__(256)
void gemv32(const float* __restrict__ W, const float* __restrict__ X,
            float* __restrict__ C, int K, long strideB)
{
    __shared__ __align__(16) float xs[32][68];   // +4 pad: conflict-free
    __shared__ __align__(16) float wt[64][68];
    const int tid = threadIdx.x;
    const int bg  = tid & 7;          // 8 b-groups, b = bg + 8j
    const int mg  = tid >> 3;         // 0..31 -> rows 2mg, 2mg+1
    const int row0 = blockIdx.x * 64;
    const int ks   = K / gridDim.y;
    const int kbeg = blockIdx.y * ks;
    const int kend = kbeg + ks;

    float acc[2][4] = {};

    for (int k0 = kbeg; k0 < kend; k0 += 64) {
        // stage X tile (32 x 64)
        for (int i = tid; i < 32 * 16; i += 256) {
            int b = i >> 4, kq = i & 15;
            float4 v = *(const float4*)(X + (long)b * K + k0 + kq * 4);
            *(float4*)&xs[b][kq * 4] = v;
        }
        // stage W tile (64 x 64)
        for (int i = tid; i < 64 * 16; i += 256) {
            int m = i >> 4, kq = i & 15;
            float4 v = *(const float4*)(W + (long)(row0 + m) * K + k0 + kq * 4);
            *(float4*)&wt[m][kq * 4] = v;
        }
        __syncthreads();
        #pragma unroll
        for (int kq = 0; kq < 16; ++kq) {
            float4 w0 = *(const float4*)&wt[mg * 2 + 0][kq * 4];
            float4 w1 = *(const float4*)&wt[mg * 2 + 1][kq * 4];
            #pragma unroll
            for (int j = 0; j < 4; ++j) {
                float4 xv = *(const float4*)&xs[bg + 8 * j][kq * 4];
                acc[0][j] = fmaf(w0.x, xv.x, acc[0][j]);
                acc[0][j] = fmaf(w0.y, xv.y, acc[0][j]);
                acc[0][j] = fmaf(w0.z, xv.z, acc[0][j]);
                acc[0][j] = fmaf(w0.w, xv.w, acc[0][j]);
                acc[1][j] = fmaf(w1.x, xv.x, acc[1][j]);
                acc[1][j] = fmaf(w1.y, xv.y, acc[1][j]);
                acc[1][j] = fmaf(w1.z, xv.z, acc[1][j]);
                acc[1][j] = fmaf(w1.w, xv.w, acc[1][j]);
            }
        }
        __syncthreads();
    }
    #pragma unroll
    for (int j = 0; j < 4; ++j) {
        int b = bg + 8 * j;
        atomicAdd(&C[(long)b * strideB + row0 + mg * 2 + 0], acc[0][j]);
        atomicAdd(&C[(long)b * strideB + row0 + mg * 2 + 1], acc[1][j]);
    }
}

// ---------------------------------------------------------------------------
// RoPE on q (in-place) and k (k_new -> k_cache[b][start]), copy v into cache.
// One block per batch b.
// ---------------------------------------------------------------------------
__global__ __launch_bounds__(256)
void rope_scatter(float* __restrict__ q_buf, const float* __restrict__ k_new,
                  const float* __restrict__ v_new, float* __restrict__ k_cache,
                  float* __restrict__ v_cache, const float* __restrict__ fc,
                  const float* __restrict__ fs, const int* __restrict__ sp)
{
    const int b = blockIdx.x, tid = threadIdx.x;
    const int start = sp[0];
    // q rope: HQ heads x 64 pairs
    for (int i = tid; i < HQ * 64; i += 256) {
        int hh = i >> 6, p = i & 63;
        float c = fc[p], s = fs[p];
        long o = (long)b * DIM + hh * HD + 2 * p;
        float xr = q_buf[o], xi = q_buf[o + 1];
        q_buf[o]     = xr * c - xi * s;
        q_buf[o + 1] = xr * s + xi * c;
    }
    // k rope + scatter
    for (int i = tid; i < HKV * 64; i += 256) {
        int gg = i >> 6, p = i & 63;
        float c = fc[p], s = fs[p];
        long src = (long)b * (HKV * HD) + gg * HD + 2 * p;
        float xr = k_new[src], xi = k_new[src + 1];
        long dst = ((long)b * MAXS + start) * (HKV * HD) + gg * HD + 2 * p;
        k_cache[dst]     = xr * c - xi * s;
        k_cache[dst + 1] = xr * s + xi * c;
    }
    // v scatter
    for (int i = tid; i < HKV * HD; i += 256) {
        v_cache[((long)b * MAXS + start) * (HKV * HD) + i] =
            v_new[(long)b * (HKV * HD) + i];
    }
}

// ---------------------------------------------------------------------------
// GQA attention, one block per (kv-group g, batch b). 512 threads = 8 waves.
// Pass 1: scores (4 q-heads share this block's K stream), softmax in LDS,
// Pass 2: P·V with coalesced V stream read once.
// ---------------------------------------------------------------------------
__global__ __launch_bounds__(512)
void attention(const float* __restrict__ q_buf, const float* __restrict__ k_cache,
               const float* __restrict__ v_cache, float* __restrict__ attn,
               const int* __restrict__ sp)
{
    const int g = blockIdx.x, b = blockIdx.y;
    const int tid = threadIdx.x;
    const int wave = tid >> 6, lane = tid & 63;
    const int L = sp[0] + 1;   // 2048

    __shared__ __align__(16) float qs[4 * HD];        // 2 KB
    __shared__ __align__(16) float sc[4 * MAXS];      // 32 KB
    __shared__ __align__(16) float outred[16 * HD];   // 8 KB
    __shared__ float wred[8];
    __shared__ float m_sh[4], inv_sh[4];

    for (int i = tid; i < 4 * HD; i += 512)
        qs[i] = q_buf[(long)b * DIM + g * 4 * HD + i];
    __syncthreads();

    const float scale = 0.08838834764831845f;  // 1/sqrt(128)
    const float* Kbase = k_cache + ((long)b * MAXS * HKV + g) * HD;

    // ---- pass 1: scores -------------------------------------------------
    {
        const int r = lane & 3, tr = lane >> 2;   // head, t-row within group
        for (int grp = 0; grp < 16; ++grp) {
            int t = wave * 256 + grp * 16 + tr;
            const float* Kt = Kbase + (long)t * (HKV * HD);
            float a0 = 0.f, a1 = 0.f;
            #pragma unroll
            for (int kq = 0; kq < 16; ++kq) {
                float4 kv = *(const float4*)(Kt + kq * 4);
                float4 qv = *(const float4*)(qs + r * HD + kq * 4);
                a0 = fmaf(kv.x, qv.x, a0);
                a0 = fmaf(kv.y, qv.y, a0);
                a0 = fmaf(kv.z, qv.z, a0);
                a0 = fmaf(kv.w, qv.w, a0);
            }
            #pragma unroll
            for (int kq = 16; kq < 32; ++kq) {
                float4 kv = *(const float4*)(Kt + kq * 4);
                float4 qv = *(const float4*)(qs + r * HD + kq * 4);
                a1 = fmaf(kv.x, qv.x, a1);
                a1 = fmaf(kv.y, qv.y, a1);
                a1 = fmaf(kv.z, qv.z, a1);
                a1 = fmaf(kv.w, qv.w, a1);
            }
            if (t < L) sc[r * MAXS + t] = (a0 + a1) * scale;
        }
    }
    __syncthreads();

    // ---- softmax --------------------------------------------------------
    const int h = tid >> 7, idx = tid & 127;
    {
        float mx = -3.0e38f;
        for (int t = idx; t < L; t += 128) mx = fmaxf(mx, sc[h * MAXS + t]);
        #pragma unroll
        for (int o = 32; o > 0; o >>= 1) mx = fmaxf(mx, __shfl_xor(mx, o, 64));
        if (lane == 0) wred[wave] = mx;
        __syncthreads();
        if (tid < 4) m_sh[tid] = fmaxf(wred[2 * tid], wred[2 * tid + 1]);
        __syncthreads();
        float m = m_sh[h];
        float s = 0.f;
        for (int t = idx; t < L; t += 128) {
            float p = __expf(sc[h * MAXS + t] - m);
            sc[h * MAXS + t] = p;
            s += p;
        }
        #pragma unroll
        for (int o = 32; o > 0; o >>= 1) s += __shfl_xor(s, o, 64);
        if (lane == 0) wred[wave] = s;
        __syncthreads();
        if (tid < 4) inv_sh[tid] = 1.0f / (wred[2 * tid] + wred[2 * tid + 1]);
        __syncthreads();
    }

    // ---- pass 2: P . V --------------------------------------------------
    {
        const int d = tid & 127, tc = tid >> 7;
        const float* Vd = v_cache + ((long)b * MAXS * HKV + g) * HD + d;
        float a0 = 0.f, a1 = 0.f, a2 = 0.f, a3 = 0.f;
        int t0 = tc * 512, t1 = t0 + 512; if (t1 > L) t1 = L;
        #pragma unroll 4
        for (int t = t0; t < t1; ++t) {
            float v = Vd[(long)t * (HKV * HD)];
            a0 = fmaf(sc[t], v, a0);
            a1 = fmaf(sc[MAXS + t], v, a1);
            a2 = fmaf(sc[2 * MAXS + t], v, a2);
            a3 = fmaf(sc[3 * MAXS + t], v, a3);
        }
        outred[(tc * 4 + 0) * HD + d] = a0;
        outred[(tc * 4 + 1) * HD + d] = a1;
        outred[(tc * 4 + 2) * HD + d] = a2;
        outred[(tc * 4 + 3) * HD + d] = a3;
    }
    __syncthreads();
    {
        const int d = tid & 127, hh = tid >> 7;
        float o = outred[(0 * 4 + hh) * HD + d] + outred[(1 * 4 + hh) * HD + d]
                + outred[(2 * 4 + hh) * HD + d] + outred[(3 * 4 + hh) * HD + d];
        o *= inv_sh[hh];
        attn[(long)b * DIM + g * 4 * HD + hh * HD + d] = o;
    }
}

// ---------------------------------------------------------------------------
extern "C" void kernel_launch(void* const* d_in, const int* in_sizes, int n_in,
                              void* d_out, int out_size, void* d_ws, size_t ws_size,
                              hipStream_t stream)
{
    const float* x    = (const float*)d_in[0];
    const float* fcos = (const float*)d_in[1];
    const float* fsin = (const float*)d_in[2];
    const float* wq   = (const float*)d_in[3];
    const float* wk   = (const float*)d_in[4];
    const float* wv   = (const float*)d_in[5];
    const float* wo   = (const float*)d_in[6];
    float* k_cache    = (float*)d_in[7];
    float* v_cache    = (float*)d_in[8];
    const int* sp     = (const int*)d_in[9];
    float* out        = (float*)d_out;

    float* q_buf = (float*)d_ws;            // 131072 floats
    float* k_new = q_buf + NB * DIM;        // 32768
    float* v_new = k_new + NB * HKV * HD;   // 32768
    float* attn  = v_new + NB * HKV * HD;   // 131072 (no zeroing needed)

    // zero atomic targets (q_buf, k_new, v_new) and d_out
    hipMemsetAsync(d_ws, 0, (size_t)(NB * DIM + 2 * NB * HKV * HD) * 4, stream);
    hipMemsetAsync(d_out, 0, (size_t)NB * DIM * 4, stream);

    gemv32<<<dim3(64, 4), 256, 0, stream>>>(wq, x, q_buf, DIM, DIM);
    gemv32<<<dim3(16, 4), 256, 0, stream>>>(wk, x, k_new, DIM, HKV * HD);
    gemv32<<<dim3(16, 4), 256, 0, stream>>>(wv, x, v_new, DIM, HKV * HD);
    rope_scatter<<<NB, 256, 0, stream>>>(q_buf, k_new, v_new, k_cache, v_cache,
                                         fcos, fsin, sp);
    attention<<<dim3(HKV, NB), 512, 0, stream>>>(q_buf, k_cache, v_cache, attn, sp);
    gemv32<<<dim3(64, 4), 256, 0, stream>>>(wo, attn, out, DIM, DIM);
}